// Round 3
// baseline (623.120 us; speedup 1.0000x reference)
//
#include <hip/hip_runtime.h>
#include <cstdint>
#include <cstddef>

typedef short s8vec __attribute__((ext_vector_type(8)));     // 8 bf16 (4 VGPRs)
typedef float f16acc __attribute__((ext_vector_type(16)));   // 16 fp32 acc

#define C_DIM 256
#define M_DIM 16384
#define BATCH 8
#define KSPLIT 32
#define KCHUNK 512
#define BK 64
#define LDSP 72   // cov LDS pitch in bf16 elems (0 bank conflicts measured)
#define TP 40     // ns_tail LDS pitch for 32-wide k-slab

static __device__ __forceinline__ unsigned short f2bf(float f) {
    union { float f; unsigned u; } v; v.f = f;
    unsigned r = v.u + 0x7fffu + ((v.u >> 16) & 1u);  // round-to-nearest-even
    return (unsigned short)(r >> 16);
}
static __device__ __forceinline__ float bf2f(unsigned short h) {
    union { unsigned u; float f; } v; v.u = ((unsigned)h) << 16;
    return v.f;
}

// ---------------------------------------------------------------------------
// cov partial, symmetric 3-tile: block computes one 128x128 quadrant of
// Xchunk @ Xchunk^T. tile 0:(0,0) 1:(1,1) 2:(1,0); (0,1) mirrored later.
// grid (3, KSPLIT, BATCH), 256 threads = 4 waves (2x2), 64x64 per wave.
// launch_bounds (256,4): 4 blk/CU (VGPR 108, LDS 36.9KB); (256,2) was
// latency-bound at 17% occupancy / 28% HBM.
// ---------------------------------------------------------------------------
__global__ __launch_bounds__(256, 4)
void cov_kernel(const float* __restrict__ x, float* __restrict__ covraw,
                float* __restrict__ sums)
{
    __shared__ unsigned short As[128][LDSP];
    __shared__ unsigned short Bs[128][LDSP];
    const int tile = blockIdx.x;                  // 0,1,2
    const int kc   = blockIdx.y;
    const int b    = blockIdx.z;
    const int trow = (tile == 0) ? 0 : 128;
    const int tcol = (tile == 2) ? 0 : trow;
    const bool diag = (tile < 2);

    const int tid  = threadIdx.x;
    const int lane = tid & 63;
    const int wave = tid >> 6;      // 0..3
    const int wr = wave >> 1, wc = wave & 1;
    const int half = lane >> 5, l31 = lane & 31;

    const float* xb = x + (size_t)b * C_DIM * M_DIM + (size_t)kc * KCHUNK;

    f16acc acc[2][2] = {};
    float rowsum[8] = {0,0,0,0,0,0,0,0};
    const int sr = tid >> 4;          // 0..15
    const int sc = (tid & 15) * 4;    // 0..60

    // prologue: load kt=0
    float4 va[8], vb[8];
    {
        const float* sa = xb + (size_t)(trow + sr) * M_DIM + sc;
        #pragma unroll
        for (int i = 0; i < 8; ++i)
            va[i] = *(const float4*)(sa + (size_t)(16 * i) * M_DIM);
        if (!diag) {
            const float* sb2 = xb + (size_t)(tcol + sr) * M_DIM + sc;
            #pragma unroll
            for (int i = 0; i < 8; ++i)
                vb[i] = *(const float4*)(sb2 + (size_t)(16 * i) * M_DIM);
        }
    }

    const unsigned short (*Bp)[LDSP] = diag ? As : Bs;

    for (int kt = 0; kt < KCHUNK / BK; ++kt) {
        __syncthreads();   // previous kt's LDS consumers done
        #pragma unroll
        for (int i = 0; i < 8; ++i) {
            if (diag) rowsum[i] += va[i].x + va[i].y + va[i].z + va[i].w;
            ushort4 p;
            p.x = f2bf(va[i].x); p.y = f2bf(va[i].y);
            p.z = f2bf(va[i].z); p.w = f2bf(va[i].w);
            *(ushort4*)&As[sr + 16 * i][sc] = p;
        }
        if (!diag) {
            #pragma unroll
            for (int i = 0; i < 8; ++i) {
                ushort4 p;
                p.x = f2bf(vb[i].x); p.y = f2bf(vb[i].y);
                p.z = f2bf(vb[i].z); p.w = f2bf(vb[i].w);
                *(ushort4*)&Bs[sr + 16 * i][sc] = p;
            }
        }
        // prefetch next tile
        if (kt < KCHUNK / BK - 1) {
            const float* sa = xb + (size_t)(trow + sr) * M_DIM + (kt + 1) * BK + sc;
            #pragma unroll
            for (int i = 0; i < 8; ++i)
                va[i] = *(const float4*)(sa + (size_t)(16 * i) * M_DIM);
            if (!diag) {
                const float* sb2 = xb + (size_t)(tcol + sr) * M_DIM + (kt + 1) * BK + sc;
                #pragma unroll
                for (int i = 0; i < 8; ++i)
                    vb[i] = *(const float4*)(sb2 + (size_t)(16 * i) * M_DIM);
            }
        }
        __syncthreads();
        #pragma unroll
        for (int ks = 0; ks < 4; ++ks) {
            const int k0 = ks * 16 + half * 8;
            s8vec af[2], bfr[2];
            #pragma unroll
            for (int i = 0; i < 2; ++i)
                af[i] = *(const s8vec*)&As[wr * 64 + i * 32 + l31][k0];
            #pragma unroll
            for (int j = 0; j < 2; ++j)
                bfr[j] = *(const s8vec*)&Bp[wc * 64 + j * 32 + l31][k0];
            #pragma unroll
            for (int i = 0; i < 2; ++i)
                #pragma unroll
                for (int j = 0; j < 2; ++j)
                    acc[i][j] = __builtin_amdgcn_mfma_f32_32x32x16_bf16(
                        af[i], bfr[j], acc[i][j], 0, 0, 0);
        }
    }
    if (diag) {
        // 16 consecutive lanes share one staged row
        #pragma unroll
        for (int i = 0; i < 8; ++i) {
            float s = rowsum[i];
            s += __shfl_down(s, 8, 16);
            s += __shfl_down(s, 4, 16);
            s += __shfl_down(s, 2, 16);
            s += __shfl_down(s, 1, 16);
            if ((lane & 15) == 0)
                atomicAdd(&sums[b * C_DIM + trow + sr + 16 * i], s);
        }
    }
    float* covb = covraw + (size_t)b * C_DIM * C_DIM;
    #pragma unroll
    for (int i = 0; i < 2; ++i) {
        const int rb = trow + wr * 64 + i * 32 + 4 * half;
        #pragma unroll
        for (int j = 0; j < 2; ++j) {
            const int cb = tcol + wc * 64 + j * 32 + l31;
            #pragma unroll
            for (int r = 0; r < 16; ++r) {
                const int row = rb + (r & 3) + 8 * (r >> 2);
                atomicAdd(&covb[row * C_DIM + cb], acc[i][j][r]);
            }
        }
    }
}

// ---------------------------------------------------------------------------
// one full 256x256x256 GEMM stage inside a 1024-thread block (16 waves, 4x4
// wave grid, 64x64 per wave as 2x2 MFMA 32x32 tiles). C = c0*I + c1*(A @ B^T)
// == c0*I + c1*A@B since all NS iterates are symmetric. K staged in 32-wide
// slabs through LDS (20KB x2, fits the 64KB static-LDS limit).
// Ends with __syncthreads so C is block-visible for the next stage.
// ---------------------------------------------------------------------------
static __device__ __forceinline__ void gstage(
    const unsigned short* __restrict__ A, const unsigned short* __restrict__ B,
    unsigned short* __restrict__ C, float c0, float c1, int tid,
    unsigned short (*As)[TP], unsigned short (*Bs)[TP])
{
    const int lane = tid & 63, wave = tid >> 6;   // 0..15
    const int wr = wave >> 2, wc = wave & 3;
    const int half = lane >> 5, l31 = lane & 31;
    const int sr  = tid >> 2;        // 0..255 (staging row)
    const int sc8 = (tid & 3) * 8;   // 0..24  (staging col, elems)

    f16acc acc[2][2] = {};
    for (int kt = 0; kt < 8; ++kt) {
        const int kb = kt * 32;
        uint4 va = *(const uint4*)(A + (size_t)sr * 256 + kb + sc8);
        uint4 vb = *(const uint4*)(B + (size_t)sr * 256 + kb + sc8);
        __syncthreads();             // previous slab's MFMA reads done
        *(uint4*)&As[sr][sc8] = va;
        *(uint4*)&Bs[sr][sc8] = vb;
        __syncthreads();
        #pragma unroll
        for (int ks = 0; ks < 2; ++ks) {
            const int k0 = ks * 16 + half * 8;
            s8vec af[2], bfr[2];
            af[0] = *(const s8vec*)&As[wr * 64 + l31][k0];
            af[1] = *(const s8vec*)&As[wr * 64 + 32 + l31][k0];
            bfr[0] = *(const s8vec*)&Bs[wc * 64 + l31][k0];
            bfr[1] = *(const s8vec*)&Bs[wc * 64 + 32 + l31][k0];
            #pragma unroll
            for (int i = 0; i < 2; ++i)
                #pragma unroll
                for (int j = 0; j < 2; ++j)
                    acc[i][j] = __builtin_amdgcn_mfma_f32_32x32x16_bf16(
                        af[i], bfr[j], acc[i][j], 0, 0, 0);
        }
    }
    #pragma unroll
    for (int i = 0; i < 2; ++i) {
        const int rb = wr * 64 + i * 32 + 4 * half;
        #pragma unroll
        for (int j = 0; j < 2; ++j) {
            const int cbc = wc * 64 + j * 32 + l31;
            #pragma unroll
            for (int r = 0; r < 16; ++r) {
                const int row = rb + (r & 3) + 8 * (r >> 2);
                float v = c1 * acc[i][j][r] + ((row == cbc) ? c0 : 0.0f);
                C[row * 256 + cbc] = f2bf(v);
            }
        }
    }
    __syncthreads();   // C visible to whole block before next stage reads it
}

// ---------------------------------------------------------------------------
// ns_tail: entire middle phase for one batch per block (8 blocks x 1024 thr).
// normsq -> emit Y0/T0 -> 12 GEMM stages (NS iters, round-0-proven sequence)
// -> gating. Serial chain stays on-chip: __syncthreads replaces 12 kernel
// launches; global bf16 ping-pong buffers are L2-resident.
// ---------------------------------------------------------------------------
__global__ __launch_bounds__(1024, 4)
void ns_tail(const float* __restrict__ covraw, const float* __restrict__ sums,
             unsigned short* __restrict__ Ya, unsigned short* __restrict__ Yb,
             unsigned short* __restrict__ Za, unsigned short* __restrict__ Zb,
             unsigned short* __restrict__ Tm,
             const float* __restrict__ w1, const float* __restrict__ b1,
             const float* __restrict__ w2, const float* __restrict__ b2,
             float* __restrict__ g)
{
    __shared__ unsigned short As[256][TP];   // 20 KB
    __shared__ unsigned short Bs[256][TP];   // 20 KB
    __shared__ float red[16];
    __shared__ float scl[2];                 // [0]=rsqrt(nq), [1]=normA=sqrt(nq)
    __shared__ float partial[4][256];
    __shared__ float xs[256];
    __shared__ float sh[32];

    const int b   = blockIdx.x;
    const int tid = threadIdx.x;
    const float invM = 1.0f / (float)M_DIM;
    const float* cb = covraw + (size_t)b * 65536;
    const float* sb = sums + b * 256;

    // ---- pass 1: normsq (mirror the unwritten (0,1) quadrant) ----
    float ss = 0.0f;
    #pragma unroll 4
    for (int i = 0; i < 64; ++i) {
        const int e = i * 1024 + tid;
        const int r = e >> 8, c = e & 255;
        const float raw = (r < 128 && c >= 128) ? cb[c * 256 + r] : cb[e];
        const float v = raw * invM - (sb[r] * invM) * (sb[c] * invM);
        ss += v * v;
    }
    #pragma unroll
    for (int off = 32; off; off >>= 1) ss += __shfl_down(ss, off, 64);
    if ((tid & 63) == 0) red[tid >> 6] = ss;
    __syncthreads();
    if (tid == 0) {
        float t = 0.0f;
        #pragma unroll
        for (int i = 0; i < 16; ++i) t += red[i];
        scl[0] = rsqrtf(t);
        scl[1] = sqrtf(t);
    }
    __syncthreads();
    const float inv = scl[0];

    // ---- pass 2: emit Y0 -> Ya, T0 (== Z1, since Z0=I) -> Za ----
    {
        unsigned short* yb_ = Ya + (size_t)b * 65536;
        unsigned short* tb_ = Za + (size_t)b * 65536;
        #pragma unroll 4
        for (int i = 0; i < 64; ++i) {
            const int e = i * 1024 + tid;
            const int r = e >> 8, c = e & 255;
            const float raw = (r < 128 && c >= 128) ? cb[c * 256 + r] : cb[e];
            const float v = (raw * invM - (sb[r] * invM) * (sb[c] * invM)) * inv;
            yb_[e] = f2bf(v);
            tb_[e] = f2bf(((r == c) ? 1.5f : 0.0f) - 0.5f * v);
        }
    }
    __syncthreads();

    // ---- NS iterations (identical sequence/numerics to round-0 kernels) ----
    const size_t mo = (size_t)b * 65536;
    unsigned short *ya = Ya + mo, *yb2 = Yb + mo, *za = Za + mo,
                   *zb = Zb + mo, *tm = Tm + mo;

    // Y1 = Y0 @ T0
    gstage(ya, za, yb2, 0.0f, 1.0f, tid, As, Bs);
    unsigned short *Yc = yb2, *Yo = ya, *Zc = za, *Zo = zb;
    for (int it = 0; it < 4; ++it) {
        // T = 1.5 I - 0.5 * Z @ Y
        gstage(Zc, Yc, tm, 1.5f, -0.5f, tid, As, Bs);
        if (it < 3) {
            gstage(Yc, tm, Yo, 0.0f, 1.0f, tid, As, Bs);   // Ynew = Y @ T
            gstage(tm, Zc, Zo, 0.0f, 1.0f, tid, As, Bs);   // Znew = T @ Z
            unsigned short* t0 = Yc; Yc = Yo; Yo = t0;
            unsigned short* t1 = Zc; Zc = Zo; Zo = t1;
        } else {
            gstage(tm, Zc, Zo, 0.0f, 1.0f, tid, As, Bs);   // Z5 = T @ Z4
            Zc = Zo;
        }
    }

    // ---- gating: y = rowmean(Z5)/sqrt(normA); h = relu(y@w1^T+b1);
    //      g = sigmoid(h@w2^T+b2). All 1024 threads hit every barrier. ----
    {
        const int row = tid & 255, qb = tid >> 8;   // 4 threads per row
        const unsigned short* zr = Zc + (size_t)row * 256 + qb * 64;
        float s = 0.0f;
        #pragma unroll
        for (int i = 0; i < 8; ++i) {
            uint4 v = *(const uint4*)(zr + i * 8);
            const unsigned short* p = (const unsigned short*)&v;
            #pragma unroll
            for (int j = 0; j < 8; ++j) s += bf2f(p[j]);
        }
        partial[qb][row] = s;
    }
    __syncthreads();
    if (tid < 256) {
        const float scale = (1.0f / 256.0f) / sqrtf(scl[1]);
        xs[tid] = (partial[0][tid] + partial[1][tid] +
                   partial[2][tid] + partial[3][tid]) * scale;
    }
    __syncthreads();
    if (tid < 32) {
        float hh = b1[tid];
        const float* w1r = w1 + tid * 256;
        for (int c2 = 0; c2 < 256; ++c2) hh += w1r[c2] * xs[c2];
        sh[tid] = hh > 0.0f ? hh : 0.0f;
    }
    __syncthreads();
    if (tid < 256) {
        float z = b2[tid];
        const float* w2r = w2 + tid * 32;
        #pragma unroll
        for (int j = 0; j < 32; ++j) z += w2r[j] * sh[j];
        g[b * 256 + tid] = 1.0f / (1.0f + expf(-z));
    }
}

// ---------------------------------------------------------------------------
// scale: out = x * g[b,c]
// ---------------------------------------------------------------------------
__global__ __launch_bounds__(256)
void scale_kernel(const float* __restrict__ x, const float* __restrict__ g,
                  float* __restrict__ out)
{
    const float4* x4 = (const float4*)x;
    float4* o4 = (float4*)out;
    #pragma unroll
    for (int it = 0; it < 4; ++it) {
        size_t i = (size_t)blockIdx.x * 1024 + it * 256 + threadIdx.x;
        float gg = g[i >> 12];
        float4 v = x4[i];
        float4 r;
        r.x = v.x * gg; r.y = v.y * gg; r.z = v.z * gg; r.w = v.w * gg;
        o4[i] = r;
    }
}

extern "C" void kernel_launch(void* const* d_in, const int* in_sizes, int n_in,
                              void* d_out, int out_size, void* d_ws, size_t ws_size,
                              hipStream_t stream)
{
    const float* x  = (const float*)d_in[0];
    const float* w1 = (const float*)d_in[1];
    const float* b1 = (const float*)d_in[2];
    const float* w2 = (const float*)d_in[3];
    const float* b2 = (const float*)d_in[4];
    float* out = (float*)d_out;

    char* ws = (char*)d_ws;
    float* covraw = (float*)ws;                        // 2 MB fp32
    float* sums   = (float*)(ws + 2097152);            // 8 KB
    float* g      = (float*)(ws + 2106368);            // 8 KB
    unsigned short* Ya = (unsigned short*)(ws + 4194304);
    unsigned short* Yb = (unsigned short*)(ws + 5242880);
    unsigned short* Za = (unsigned short*)(ws + 6291456);
    unsigned short* Zb = (unsigned short*)(ws + 7340032);
    unsigned short* Tm = (unsigned short*)(ws + 8388608);  // 1 MB, total 9.44 MB

    hipMemsetAsync(covraw, 0, 2105344, stream);  // covraw + sums

    cov_kernel<<<dim3(3, KSPLIT, BATCH), 256, 0, stream>>>(x, covraw, sums);

    ns_tail<<<dim3(BATCH), 1024, 0, stream>>>(covraw, sums, Ya, Yb, Za, Zb, Tm,
                                              w1, b1, w2, b2, g);

    scale_kernel<<<8192, 256, 0, stream>>>(x, g, out);
}